// Round 1
// 14475.227 us; speedup vs baseline: 1.2052x; 1.2052x over previous
//
#include <hip/hip_runtime.h>
#include <math.h>

#define Lnum 4
#define Hn 8
#define Cc 512
#define Tt 2048
#define Vv 50257
#define HDim 64
#define FF 2048
#define BT 4096   // B*T rows

#define GF_RESID 1
#define GF_RELU  2
#define GF_OUTBF16 4

typedef __attribute__((ext_vector_type(8))) __bf16 bf16x8;
typedef __attribute__((ext_vector_type(16))) float f32x16;

__device__ inline float waveReduceSum(float v) {
    for (int o = 32; o; o >>= 1) v += __shfl_down(v, o, 64);
    return v;
}
__device__ inline float waveReduceMax(float v) {
    for (int o = 32; o; o >>= 1) v = fmaxf(v, __shfl_down(v, o, 64));
    return v;
}

// fp32 -> bf16 bits, RNE
__device__ inline unsigned short f2bf(float x) {
    unsigned u = __float_as_uint(x);
    u += 0x7fffu + ((u >> 16) & 1u);
    return (unsigned short)(u >> 16);
}
__device__ inline float bf2f(unsigned short h) {
    return __uint_as_float((unsigned)h << 16);
}

// -------------------- embedding --------------------
__global__ __launch_bounds__(256) void embed_k(const int* __restrict__ xi,
                                               const float* __restrict__ tok,
                                               const float* __restrict__ pos,
                                               float* __restrict__ h) {
    int idx = blockIdx.x * 256 + threadIdx.x;   // BT*C total
    int row = idx >> 9;        // /512
    int c = idx & 511;
    int t = row & (Tt - 1);
    int token = xi[row];
    h[idx] = tok[(size_t)token * Cc + c] + pos[(size_t)t * Cc + c];
}

// -------------------- layernorm (row of 512), fp32 or bf16-hi/lo output ----
__global__ __launch_bounds__(256) void ln_k(const float* __restrict__ x,
                                            const float* __restrict__ g,
                                            const float* __restrict__ b,
                                            float* __restrict__ of,
                                            unsigned short* __restrict__ ohi,
                                            unsigned short* __restrict__ olo) {
    __shared__ float redA[8];
    int row = blockIdx.x;
    int tid = threadIdx.x, lane = tid & 63, w = tid >> 6;
    const float* xr = x + (size_t)row * Cc;
    float v0 = xr[tid], v1 = xr[tid + 256];
    float s = v0 + v1, sq = v0 * v0 + v1 * v1;
    s = waveReduceSum(s);
    sq = waveReduceSum(sq);
    if (lane == 0) { redA[w] = s; redA[4 + w] = sq; }
    __syncthreads();
    if (tid == 0) {
        redA[0] = redA[0] + redA[1] + redA[2] + redA[3];
        redA[4] = redA[4] + redA[5] + redA[6] + redA[7];
    }
    __syncthreads();
    float mean = redA[0] * (1.0f / Cc);
    float var = redA[4] * (1.0f / Cc) - mean * mean;
    float rstd = rsqrtf(var + 1e-5f);
    float y0 = (v0 - mean) * rstd * g[tid] + b[tid];
    float y1 = (v1 - mean) * rstd * g[tid + 256] + b[tid + 256];
    size_t o0 = (size_t)row * Cc + tid;
    if (ohi) {
        unsigned short h0 = f2bf(y0), h1 = f2bf(y1);
        ohi[o0] = h0;       olo[o0] = f2bf(y0 - bf2f(h0));
        ohi[o0 + 256] = h1; olo[o0 + 256] = f2bf(y1 - bf2f(h1));
    } else {
        of[o0] = y0;
        of[o0 + 256] = y1;
    }
}

// -------------------- OLD generic tiled fp32 GEMM (fallback path) ----------
__global__ __launch_bounds__(256) void gemm_k(const float* __restrict__ A,
                                              const float* __restrict__ W,
                                              const float* __restrict__ bias,
                                              float* __restrict__ Cmat,
                                              int M, int N, int K,
                                              int w_ldk, int w_ldh, int hd_shift,
                                              int flags) {
    __shared__ __align__(16) float As[16][64];
    __shared__ __align__(16) float Bs[16][64];
    int tid = threadIdx.x;
    int tr = tid >> 4, tc = tid & 15;
    int row0 = blockIdx.y * 64;
    int col0 = blockIdx.x * 64;

    int aE = tid * 4;
    int am = aE >> 4;
    int ak = aE & 15;
    int bE = tid * 4;
    int bk = bE >> 6;
    int bn = bE & 63;
    unsigned mask = (1u << hd_shift) - 1u;

    float acc[4][4] = {{0.f}};

    for (int kk = 0; kk < K; kk += 16) {
        float4 av = *(const float4*)(A + (size_t)(row0 + am) * K + kk + ak);
        As[ak + 0][am] = av.x;
        As[ak + 1][am] = av.y;
        As[ak + 2][am] = av.z;
        As[ak + 3][am] = av.w;
#pragma unroll
        for (int i = 0; i < 4; i++) {
            int col = col0 + bn + i;
            float bvv = 0.f;
            if (col < N)
                bvv = W[(size_t)(kk + bk) * w_ldk +
                        (size_t)(col >> hd_shift) * w_ldh + (col & mask)];
            Bs[bk][bn + i] = bvv;
        }
        __syncthreads();
#pragma unroll
        for (int k2 = 0; k2 < 16; k2++) {
            float4 a4 = *(const float4*)&As[k2][tr * 4];
            float4 b4 = *(const float4*)&Bs[k2][tc * 4];
            acc[0][0] += a4.x * b4.x; acc[0][1] += a4.x * b4.y;
            acc[0][2] += a4.x * b4.z; acc[0][3] += a4.x * b4.w;
            acc[1][0] += a4.y * b4.x; acc[1][1] += a4.y * b4.y;
            acc[1][2] += a4.y * b4.z; acc[1][3] += a4.y * b4.w;
            acc[2][0] += a4.z * b4.x; acc[2][1] += a4.z * b4.y;
            acc[2][2] += a4.z * b4.z; acc[2][3] += a4.z * b4.w;
            acc[3][0] += a4.w * b4.x; acc[3][1] += a4.w * b4.y;
            acc[3][2] += a4.w * b4.z; acc[3][3] += a4.w * b4.w;
        }
        __syncthreads();
    }

#pragma unroll
    for (int i = 0; i < 4; i++) {
#pragma unroll
        for (int j = 0; j < 4; j++) {
            int col = col0 + tc * 4 + j;
            if (col < N) {
                size_t idx = (size_t)(row0 + tr * 4 + i) * N + col;
                float vv = acc[i][j];
                if (bias) vv += bias[col];
                if (flags & GF_RELU) vv = fmaxf(vv, 0.f);
                if (flags & GF_RESID) vv += Cmat[idx];
                Cmat[idx] = vv;
            }
        }
    }
}

// -------------------- weight transpose+convert: W[k][n] -> bf16 hi/lo [N][K]
__global__ __launch_bounds__(256) void wt_k(const float* __restrict__ W,
                                            unsigned short* __restrict__ Thi,
                                            unsigned short* __restrict__ Tlo,
                                            int N, int K,
                                            int w_ldk, int w_ldh, int hd_shift) {
    __shared__ float t[32][33];
    int kt = blockIdx.x * 32, nt = blockIdx.y * 32;
    int tid = threadIdx.x;
    int r = tid >> 5, c = tid & 31;
    unsigned mask = (1u << hd_shift) - 1u;
#pragma unroll
    for (int i = 0; i < 4; i++) {
        int k = kt + r + i * 8, n = nt + c;
        float x = 0.f;
        if (n < N)
            x = W[(size_t)k * w_ldk + (size_t)(n >> hd_shift) * w_ldh + (n & mask)];
        t[r + i * 8][c] = x;
    }
    __syncthreads();
#pragma unroll
    for (int i = 0; i < 4; i++) {
        int n = nt + r + i * 8, k = kt + c;
        if (n < N) {
            float x = t[c][r + i * 8];
            unsigned short hi = f2bf(x);
            Thi[(size_t)n * K + k] = hi;
            Tlo[(size_t)n * K + k] = f2bf(x - bf2f(hi));
        }
    }
}

// -------------------- split-bf16 MFMA GEMM core helpers --------------------
__device__ inline void wb_frag(f32x16 v, int rbase, int cbase, int N,
                               const float* __restrict__ bias,
                               float* __restrict__ Cf,
                               unsigned short* __restrict__ Chi,
                               unsigned short* __restrict__ Clo,
                               int flags, int l31, int l5) {
    int col = cbase + l31;
    if (col >= N) return;
    float bv = bias ? bias[col] : 0.0f;
#pragma unroll
    for (int r = 0; r < 16; r++) {
        int row = rbase + (r & 3) + ((r >> 2) << 3) + (l5 << 2);
        size_t idx = (size_t)row * N + col;
        float xv = v[r] + bv;
        if (flags & GF_RELU) xv = fmaxf(xv, 0.0f);
        if (flags & GF_RESID) xv += Cf[idx];
        if (flags & GF_OUTBF16) {
            unsigned short hv = f2bf(xv);
            Chi[idx] = hv;
            Clo[idx] = f2bf(xv - bf2f(hv));
        } else {
            Cf[idx] = xv;
        }
    }
}

#define MFMA3(ACC, AH, AL, BH, BL)                                             \
    ACC = __builtin_amdgcn_mfma_f32_32x32x16_bf16(AH, BH, ACC, 0, 0, 0);       \
    ACC = __builtin_amdgcn_mfma_f32_32x32x16_bf16(AH, BL, ACC, 0, 0, 0);       \
    ACC = __builtin_amdgcn_mfma_f32_32x32x16_bf16(AL, BH, ACC, 0, 0, 0);

// C[M,N] = (Ahi+Alo)[M,K] @ (Whi+Wlo)^T ; W pre-transposed bf16 [N][K].
// 128x128 tile, BK=32, 4 waves of 64x64 (2x2 x 32x32 frags), 3-product split.
__global__ __launch_bounds__(256) void gemm_mfma(
    const unsigned short* __restrict__ Ahg, const unsigned short* __restrict__ Alg,
    const unsigned short* __restrict__ Whg, const unsigned short* __restrict__ Wlg,
    const float* __restrict__ bias, float* __restrict__ Cf,
    unsigned short* __restrict__ Chi, unsigned short* __restrict__ Clo,
    int N, int K, int flags) {
    __shared__ __align__(16) unsigned short Ah[128][40];
    __shared__ __align__(16) unsigned short Al[128][40];
    __shared__ __align__(16) unsigned short Bh[128][40];
    __shared__ __align__(16) unsigned short Bl[128][40];
    int tid = threadIdx.x;
    int row0 = blockIdx.x * 128, col0 = blockIdx.y * 128;
    int sr = tid >> 1, sc = (tid & 1) << 4;       // staging: 2 thr/row, 16 bf16 each
    int lane = tid & 63, w = tid >> 6;
    int wrow = (w >> 1) << 6, wcol = (w & 1) << 6;
    int l31 = lane & 31, l5 = lane >> 5;

    const unsigned short* ap  = Ahg + (size_t)(row0 + sr) * K + sc;
    const unsigned short* alp = Alg + (size_t)(row0 + sr) * K + sc;
    int bn = col0 + sr;
    bool bok = bn < N;
    const unsigned short* bp  = Whg + (size_t)bn * K + sc;
    const unsigned short* blp = Wlg + (size_t)bn * K + sc;

    f32x16 acc00, acc01, acc10, acc11;
#pragma unroll
    for (int r = 0; r < 16; r++) {
        acc00[r] = 0.f; acc01[r] = 0.f; acc10[r] = 0.f; acc11[r] = 0.f;
    }

    uint4 zz; zz.x = zz.y = zz.z = zz.w = 0u;
    uint4 ra0 = *(const uint4*)(ap);
    uint4 ra1 = *(const uint4*)(ap + 8);
    uint4 ra2 = *(const uint4*)(alp);
    uint4 ra3 = *(const uint4*)(alp + 8);
    uint4 rb0 = zz, rb1 = zz, rb2 = zz, rb3 = zz;
    if (bok) {
        rb0 = *(const uint4*)(bp);
        rb1 = *(const uint4*)(bp + 8);
        rb2 = *(const uint4*)(blp);
        rb3 = *(const uint4*)(blp + 8);
    }

    for (int kk = 0; kk < K; kk += 32) {
        *(uint4*)&Ah[sr][sc] = ra0; *(uint4*)&Ah[sr][sc + 8] = ra1;
        *(uint4*)&Al[sr][sc] = ra2; *(uint4*)&Al[sr][sc + 8] = ra3;
        *(uint4*)&Bh[sr][sc] = rb0; *(uint4*)&Bh[sr][sc + 8] = rb1;
        *(uint4*)&Bl[sr][sc] = rb2; *(uint4*)&Bl[sr][sc + 8] = rb3;
        if (kk + 32 < K) {   // prefetch next tile into regs (hides HBM latency)
            int k2 = kk + 32;
            ra0 = *(const uint4*)(ap + k2);
            ra1 = *(const uint4*)(ap + k2 + 8);
            ra2 = *(const uint4*)(alp + k2);
            ra3 = *(const uint4*)(alp + k2 + 8);
            if (bok) {
                rb0 = *(const uint4*)(bp + k2);
                rb1 = *(const uint4*)(bp + k2 + 8);
                rb2 = *(const uint4*)(blp + k2);
                rb3 = *(const uint4*)(blp + k2 + 8);
            }
        }
        __syncthreads();
#pragma unroll
        for (int ks = 0; ks < 2; ks++) {
            int ko = (ks << 4) + (l5 << 3);
            bf16x8 a0h = *(const bf16x8*)&Ah[wrow + l31][ko];
            bf16x8 a1h = *(const bf16x8*)&Ah[wrow + 32 + l31][ko];
            bf16x8 a0l = *(const bf16x8*)&Al[wrow + l31][ko];
            bf16x8 a1l = *(const bf16x8*)&Al[wrow + 32 + l31][ko];
            bf16x8 b0h = *(const bf16x8*)&Bh[wcol + l31][ko];
            bf16x8 b1h = *(const bf16x8*)&Bh[wcol + 32 + l31][ko];
            bf16x8 b0l = *(const bf16x8*)&Bl[wcol + l31][ko];
            bf16x8 b1l = *(const bf16x8*)&Bl[wcol + 32 + l31][ko];
            MFMA3(acc00, a0h, a0l, b0h, b0l)
            MFMA3(acc01, a0h, a0l, b1h, b1l)
            MFMA3(acc10, a1h, a1l, b0h, b0l)
            MFMA3(acc11, a1h, a1l, b1h, b1l)
        }
        __syncthreads();
    }

    wb_frag(acc00, row0 + wrow,      col0 + wcol,      N, bias, Cf, Chi, Clo, flags, l31, l5);
    wb_frag(acc01, row0 + wrow,      col0 + wcol + 32, N, bias, Cf, Chi, Clo, flags, l31, l5);
    wb_frag(acc10, row0 + wrow + 32, col0 + wcol,      N, bias, Cf, Chi, Clo, flags, l31, l5);
    wb_frag(acc11, row0 + wrow + 32, col0 + wcol + 32, N, bias, Cf, Chi, Clo, flags, l31, l5);
}

// LM-head variant: B staged on the fly from fp32 W [K][N] (saves 103MB ws).
__global__ __launch_bounds__(256) void gemm_mfma_wf32(
    const unsigned short* __restrict__ Ahg, const unsigned short* __restrict__ Alg,
    const float* __restrict__ W, const float* __restrict__ bias,
    float* __restrict__ Cf, int N, int K) {
    __shared__ __align__(16) unsigned short Ah[128][40];
    __shared__ __align__(16) unsigned short Al[128][40];
    __shared__ __align__(16) unsigned short Bh[128][40];
    __shared__ __align__(16) unsigned short Bl[128][40];
    int tid = threadIdx.x;
    int row0 = blockIdx.x * 128, col0 = blockIdx.y * 128;
    int sr = tid >> 1, sc = (tid & 1) << 4;
    int lane = tid & 63, w = tid >> 6;
    int wrow = (w >> 1) << 6, wcol = (w & 1) << 6;
    int l31 = lane & 31, l5 = lane >> 5;
    int krow = tid >> 3, nb = tid & 7;            // B staging: 8 thr/k-row

    const unsigned short* ap  = Ahg + (size_t)(row0 + sr) * K + sc;
    const unsigned short* alp = Alg + (size_t)(row0 + sr) * K + sc;

    f32x16 acc00, acc01, acc10, acc11;
#pragma unroll
    for (int r = 0; r < 16; r++) {
        acc00[r] = 0.f; acc01[r] = 0.f; acc10[r] = 0.f; acc11[r] = 0.f;
    }

    for (int kk = 0; kk < K; kk += 32) {
        uint4 ra0 = *(const uint4*)(ap + kk);
        uint4 ra1 = *(const uint4*)(ap + kk + 8);
        uint4 ra2 = *(const uint4*)(alp + kk);
        uint4 ra3 = *(const uint4*)(alp + kk + 8);
        *(uint4*)&Ah[sr][sc] = ra0; *(uint4*)&Ah[sr][sc + 8] = ra1;
        *(uint4*)&Al[sr][sc] = ra2; *(uint4*)&Al[sr][sc + 8] = ra3;
        const float* wp = W + (size_t)(kk + krow) * N + col0 + nb;
#pragma unroll
        for (int j = 0; j < 16; j++) {
            int c = col0 + nb + (j << 3);
            float x = (c < N) ? wp[j << 3] : 0.0f;
            unsigned short hv = f2bf(x);
            Bh[nb + (j << 3)][krow] = hv;
            Bl[nb + (j << 3)][krow] = f2bf(x - bf2f(hv));
        }
        __syncthreads();
#pragma unroll
        for (int ks = 0; ks < 2; ks++) {
            int ko = (ks << 4) + (l5 << 3);
            bf16x8 a0h = *(const bf16x8*)&Ah[wrow + l31][ko];
            bf16x8 a1h = *(const bf16x8*)&Ah[wrow + 32 + l31][ko];
            bf16x8 a0l = *(const bf16x8*)&Al[wrow + l31][ko];
            bf16x8 a1l = *(const bf16x8*)&Al[wrow + 32 + l31][ko];
            bf16x8 b0h = *(const bf16x8*)&Bh[wcol + l31][ko];
            bf16x8 b1h = *(const bf16x8*)&Bh[wcol + 32 + l31][ko];
            bf16x8 b0l = *(const bf16x8*)&Bl[wcol + l31][ko];
            bf16x8 b1l = *(const bf16x8*)&Bl[wcol + 32 + l31][ko];
            MFMA3(acc00, a0h, a0l, b0h, b0l)
            MFMA3(acc01, a0h, a0l, b1h, b1l)
            MFMA3(acc10, a1h, a1l, b0h, b0l)
            MFMA3(acc11, a1h, a1l, b1h, b1l)
        }
        __syncthreads();
    }

    wb_frag(acc00, row0 + wrow,      col0 + wcol,      N, bias, Cf, nullptr, nullptr, 0, l31, l5);
    wb_frag(acc01, row0 + wrow,      col0 + wcol + 32, N, bias, Cf, nullptr, nullptr, 0, l31, l5);
    wb_frag(acc10, row0 + wrow + 32, col0 + wcol,      N, bias, Cf, nullptr, nullptr, 0, l31, l5);
    wb_frag(acc11, row0 + wrow + 32, col0 + wcol + 32, N, bias, Cf, nullptr, nullptr, 0, l31, l5);
}

// -------------------- causal attention, one (b,h,tq) per block -------------
__global__ __launch_bounds__(256) void attn_k(const float* __restrict__ q,
                                              const float* __restrict__ k,
                                              const float* __restrict__ v,
                                              float* __restrict__ outf,
                                              unsigned short* __restrict__ ohi,
                                              unsigned short* __restrict__ olo) {
    __shared__ float sc[Tt];
    __shared__ float qs[HDim];
    __shared__ float pacc[256];
    __shared__ float redA[4];
    __shared__ float fin[2];
    int tq = blockIdx.x;
    int bh = blockIdx.y;
    int b = bh >> 3, h = bh & 7;
    int tid = threadIdx.x, lane = tid & 63, w = tid >> 6;
    size_t base = (size_t)b * Tt * Cc + (size_t)h * HDim;
    if (tid < HDim) qs[tid] = q[base + (size_t)tq * Cc + tid] * 0.125f;
    __syncthreads();
    for (int s = w; s <= tq; s += 4) {
        float val = qs[lane] * k[base + (size_t)s * Cc + lane];
        val = waveReduceSum(val);
        if (lane == 0) sc[s] = val;
    }
    __syncthreads();
    float m = -3.0e38f;
    for (int i = tid; i <= tq; i += 256) m = fmaxf(m, sc[i]);
    m = waveReduceMax(m);
    if (lane == 0) redA[w] = m;
    __syncthreads();
    if (tid == 0) fin[0] = fmaxf(fmaxf(redA[0], redA[1]), fmaxf(redA[2], redA[3]));
    __syncthreads();
    m = fin[0];
    float sum = 0.f;
    for (int i = tid; i <= tq; i += 256) {
        float e = __expf(sc[i] - m);
        sc[i] = e;
        sum += e;
    }
    sum = waveReduceSum(sum);
    if (lane == 0) redA[w] = sum;
    __syncthreads();
    if (tid == 0) fin[1] = redA[0] + redA[1] + redA[2] + redA[3];
    __syncthreads();
    float inv = 1.0f / fin[1];
    float acc = 0.f;
    for (int s = w; s <= tq; s += 4)
        acc += sc[s] * v[base + (size_t)s * Cc + lane];
    pacc[tid] = acc;
    __syncthreads();
    if (w == 0) {
        float r = (pacc[lane] + pacc[64 + lane] + pacc[128 + lane] + pacc[192 + lane]) * inv;
        size_t oi = base + (size_t)tq * Cc + lane;
        if (ohi) {
            unsigned short hv = f2bf(r);
            ohi[oi] = hv;
            olo[oi] = f2bf(r - bf2f(hv));
        } else {
            outf[oi] = r;
        }
    }
}

// -------------------- per-row loss term --------------------
__global__ __launch_bounds__(256) void lse_k(const float* __restrict__ logits,
                                             const int* __restrict__ tgt,
                                             float* __restrict__ rowloss) {
    __shared__ float redA[4];
    __shared__ float fin[2];
    int r = blockIdx.x;
    int tid = threadIdx.x, lane = tid & 63, w = tid >> 6;
    const float* p = logits + (size_t)r * Vv;
    float m = -3.0e38f;
    for (int i = tid; i < Vv; i += 256) m = fmaxf(m, p[i]);
    m = waveReduceMax(m);
    if (lane == 0) redA[w] = m;
    __syncthreads();
    if (tid == 0) fin[0] = fmaxf(fmaxf(redA[0], redA[1]), fmaxf(redA[2], redA[3]));
    __syncthreads();
    float bm = fin[0];
    float sum = 0.f;
    for (int i = tid; i < Vv; i += 256) sum += __expf(p[i] - bm);
    sum = waveReduceSum(sum);
    if (lane == 0) redA[w] = sum;
    __syncthreads();
    if (tid == 0) fin[1] = redA[0] + redA[1] + redA[2] + redA[3];
    __syncthreads();
    if (tid == 0) rowloss[r] = p[tgt[r]] - bm - logf(fin[1]);
}

__global__ __launch_bounds__(256) void loss_k(const float* __restrict__ rowloss,
                                              float* __restrict__ out) {
    __shared__ float redA[4];
    int tid = threadIdx.x, lane = tid & 63, w = tid >> 6;
    float s = 0.f;
    for (int i = tid; i < BT; i += 256) s += rowloss[i];
    s = waveReduceSum(s);
    if (lane == 0) redA[w] = s;
    __syncthreads();
    if (tid == 0) out[0] = -(redA[0] + redA[1] + redA[2] + redA[3]) * (1.0f / BT);
}

extern "C" void kernel_launch(void* const* d_in, const int* in_sizes, int n_in,
                              void* d_out, int out_size, void* d_ws, size_t ws_size,
                              hipStream_t stream) {
    const int*   x     = (const int*)d_in[0];
    const int*   tgt   = (const int*)d_in[1];
    const float* tok   = (const float*)d_in[2];
    const float* pos   = (const float*)d_in[3];
    const float* ln1s  = (const float*)d_in[4];
    const float* ln1b  = (const float*)d_in[5];
    const float* wq    = (const float*)d_in[6];
    const float* wk    = (const float*)d_in[7];
    const float* wv    = (const float*)d_in[8];
    const float* wproj = (const float*)d_in[9];
    const float* bproj = (const float*)d_in[10];
    const float* ln2s  = (const float*)d_in[11];
    const float* ln2b  = (const float*)d_in[12];
    const float* wff1  = (const float*)d_in[13];
    const float* bff1  = (const float*)d_in[14];
    const float* wff2  = (const float*)d_in[15];
    const float* bff2  = (const float*)d_in[16];
    const float* lnfs  = (const float*)d_in[17];
    const float* lnfb  = (const float*)d_in[18];
    const float* lmw   = (const float*)d_in[19];
    const float* lmb   = (const float*)d_in[20];

    float* logits = (float*)d_out;
    float* lossp = logits + (size_t)BT * Vv;

    const size_t rowsC = (size_t)BT * Cc;       // 2,097,152
    const size_t midE  = (size_t)BT * FF;       // 8,388,608
    const size_t lwEl  = (size_t)Cc * Cc;       // 262,144 (qkv/proj weight elems)
    const size_t ffEl  = (size_t)Cc * FF;       // 1,048,576
    const size_t layerUS = 8 * lwEl + 4 * ffEl; // ushorts per layer of hi/lo weights

    // ---- new-path workspace layout ----
    char* p = (char*)d_ws;
    float* h  = (float*)p; p += rowsC * 4;
    float* qb = (float*)p; p += rowsC * 4;
    float* kb = (float*)p; p += rowsC * 4;
    float* vb = (float*)p; p += rowsC * 4;
    float* rowloss = (float*)p; p += (size_t)BT * 4;
    unsigned short* ahi = (unsigned short*)p; p += rowsC * 2;
    unsigned short* alo = (unsigned short*)p; p += rowsC * 2;
    unsigned short* midhi = (unsigned short*)p; p += midE * 2;
    unsigned short* midlo = (unsigned short*)p; p += midE * 2;
    unsigned short* wt = (unsigned short*)p; p += 4 * layerUS * 2;
    size_t needNew = (size_t)(p - (char*)d_ws);   // 125,845,504 bytes

    if (ws_size >= needNew) {
        // ================== MFMA split-bf16 path ==================
        // 1) weight transpose+convert passes (once per launch)
        for (int l = 0; l < Lnum; l++) {
            unsigned short* Lw = wt + (size_t)l * layerUS;
            const float* wq_l = wq + (size_t)l * Hn * Cc * HDim;
            const float* wk_l = wk + (size_t)l * Hn * Cc * HDim;
            const float* wv_l = wv + (size_t)l * Hn * Cc * HDim;
            wt_k<<<dim3(16, 16), 256, 0, stream>>>(wq_l, Lw, Lw + lwEl,
                                                   Cc, Cc, HDim, Cc * HDim, 6);
            wt_k<<<dim3(16, 16), 256, 0, stream>>>(wk_l, Lw + 2 * lwEl, Lw + 3 * lwEl,
                                                   Cc, Cc, HDim, Cc * HDim, 6);
            wt_k<<<dim3(16, 16), 256, 0, stream>>>(wv_l, Lw + 4 * lwEl, Lw + 5 * lwEl,
                                                   Cc, Cc, HDim, Cc * HDim, 6);
            wt_k<<<dim3(16, 16), 256, 0, stream>>>(wproj + (size_t)l * Cc * Cc,
                                                   Lw + 6 * lwEl, Lw + 7 * lwEl,
                                                   Cc, Cc, Cc, 0, 30);
            wt_k<<<dim3(16, 64), 256, 0, stream>>>(wff1 + (size_t)l * Cc * FF,
                                                   Lw + 8 * lwEl, Lw + 8 * lwEl + ffEl,
                                                   FF, Cc, FF, 0, 30);
            wt_k<<<dim3(64, 16), 256, 0, stream>>>(wff2 + (size_t)l * FF * Cc,
                                                   Lw + 8 * lwEl + 2 * ffEl,
                                                   Lw + 8 * lwEl + 3 * ffEl,
                                                   Cc, FF, Cc, 0, 30);
        }

        embed_k<<<(BT * Cc) / 256, 256, 0, stream>>>(x, tok, pos, h);

        dim3 g512(BT / 128, Cc / 128);   // (32, 4)
        dim3 gff1(BT / 128, FF / 128);   // (32, 16)
        dim3 gattn(Tt, 2 * Hn);

        for (int l = 0; l < Lnum; l++) {
            unsigned short* Lw = wt + (size_t)l * layerUS;
            ln_k<<<BT, 256, 0, stream>>>(h, ln1s + l * Cc, ln1b + l * Cc,
                                         nullptr, ahi, alo);
            gemm_mfma<<<g512, 256, 0, stream>>>(ahi, alo, Lw, Lw + lwEl,
                                                nullptr, qb, nullptr, nullptr,
                                                Cc, Cc, 0);
            gemm_mfma<<<g512, 256, 0, stream>>>(ahi, alo, Lw + 2 * lwEl, Lw + 3 * lwEl,
                                                nullptr, kb, nullptr, nullptr,
                                                Cc, Cc, 0);
            gemm_mfma<<<g512, 256, 0, stream>>>(ahi, alo, Lw + 4 * lwEl, Lw + 5 * lwEl,
                                                nullptr, vb, nullptr, nullptr,
                                                Cc, Cc, 0);
            attn_k<<<gattn, 256, 0, stream>>>(qb, kb, vb, nullptr, ahi, alo);
            gemm_mfma<<<g512, 256, 0, stream>>>(ahi, alo, Lw + 6 * lwEl, Lw + 7 * lwEl,
                                                bproj + l * Cc, h, nullptr, nullptr,
                                                Cc, Cc, GF_RESID);
            ln_k<<<BT, 256, 0, stream>>>(h, ln2s + l * Cc, ln2b + l * Cc,
                                         nullptr, ahi, alo);
            gemm_mfma<<<gff1, 256, 0, stream>>>(ahi, alo, Lw + 8 * lwEl,
                                                Lw + 8 * lwEl + ffEl,
                                                bff1 + l * FF, nullptr, midhi, midlo,
                                                FF, Cc, GF_RELU | GF_OUTBF16);
            gemm_mfma<<<g512, 256, 0, stream>>>(midhi, midlo, Lw + 8 * lwEl + 2 * ffEl,
                                                Lw + 8 * lwEl + 3 * ffEl,
                                                bff2 + l * Cc, h, nullptr, nullptr,
                                                Cc, FF, GF_RESID);
        }

        ln_k<<<BT, 256, 0, stream>>>(h, lnfs, lnfb, nullptr, ahi, alo);
        dim3 glm(BT / 128, (Vv + 127) / 128);   // (32, 393)
        gemm_mfma_wf32<<<glm, 256, 0, stream>>>(ahi, alo, lmw, lmb, logits, Vv, Cc);
        lse_k<<<BT, 256, 0, stream>>>(logits, tgt, rowloss);
        loss_k<<<1, 256, 0, stream>>>(rowloss, lossp);
    } else {
        // ================== fallback: original fp32 path ==================
        float* ws = (float*)d_ws;
        float* h2   = ws;
        float* a2   = h2 + rowsC;
        float* qb2  = a2 + rowsC;
        float* kb2  = qb2 + rowsC;
        float* vb2  = kb2 + rowsC;
        float* mid2 = vb2 + rowsC;                    // BT*FF
        float* rowloss2 = mid2 + (size_t)BT * FF;
        if (ws_size < (5 * rowsC + (size_t)BT * FF + BT) * sizeof(float)) return;

        embed_k<<<(BT * Cc) / 256, 256, 0, stream>>>(x, tok, pos, h2);

        dim3 g512(Cc / 64, BT / 64);
        dim3 gff1(FF / 64, BT / 64);
        dim3 gattn(Tt, 2 * Hn);

        for (int l = 0; l < Lnum; l++) {
            const float* wq_l = wq + (size_t)l * Hn * Cc * HDim;
            const float* wk_l = wk + (size_t)l * Hn * Cc * HDim;
            const float* wv_l = wv + (size_t)l * Hn * Cc * HDim;
            ln_k<<<BT, 256, 0, stream>>>(h2, ln1s + l * Cc, ln1b + l * Cc,
                                         a2, nullptr, nullptr);
            gemm_k<<<g512, 256, 0, stream>>>(a2, wq_l, nullptr, qb2, BT, Cc, Cc,
                                             HDim, Cc * HDim, 6, 0);
            gemm_k<<<g512, 256, 0, stream>>>(a2, wk_l, nullptr, kb2, BT, Cc, Cc,
                                             HDim, Cc * HDim, 6, 0);
            gemm_k<<<g512, 256, 0, stream>>>(a2, wv_l, nullptr, vb2, BT, Cc, Cc,
                                             HDim, Cc * HDim, 6, 0);
            attn_k<<<gattn, 256, 0, stream>>>(qb2, kb2, vb2, a2, nullptr, nullptr);
            gemm_k<<<g512, 256, 0, stream>>>(a2, wproj + (size_t)l * Cc * Cc,
                                             bproj + l * Cc, h2, BT, Cc, Cc,
                                             Cc, 0, 30, GF_RESID);
            ln_k<<<BT, 256, 0, stream>>>(h2, ln2s + l * Cc, ln2b + l * Cc,
                                         a2, nullptr, nullptr);
            gemm_k<<<gff1, 256, 0, stream>>>(a2, wff1 + (size_t)l * Cc * FF,
                                             bff1 + l * FF, mid2, BT, FF, Cc,
                                             FF, 0, 30, GF_RELU);
            gemm_k<<<g512, 256, 0, stream>>>(mid2, wff2 + (size_t)l * FF * Cc,
                                             bff2 + l * Cc, h2, BT, Cc, FF,
                                             Cc, 0, 30, GF_RESID);
        }

        ln_k<<<BT, 256, 0, stream>>>(h2, lnfs, lnfb, a2, nullptr, nullptr);
        dim3 glog((Vv + 63) / 64, BT / 64);
        gemm_k<<<glog, 256, 0, stream>>>(a2, lmw, lmb, logits, BT, Vv, Cc,
                                         Vv, 0, 30, 0);
        lse_k<<<BT, 256, 0, stream>>>(logits, tgt, rowloss2);
        loss_k<<<1, 256, 0, stream>>>(rowloss2, lossp);
    }
}

// Round 2
// 4755.352 us; speedup vs baseline: 3.6687x; 3.0440x over previous
//
#include <hip/hip_runtime.h>
#include <math.h>

#define Lnum 4
#define Hn 8
#define Cc 512
#define Tt 2048
#define Vv 50257
#define HDim 64
#define FF 2048
#define BT 4096   // B*T rows

#define GF_RESID 1
#define GF_RELU  2
#define GF_OUTBF16 4

typedef __attribute__((ext_vector_type(8))) __bf16 bf16x8;
typedef __attribute__((ext_vector_type(16))) float f32x16;

__device__ inline float waveReduceSum(float v) {
    for (int o = 32; o; o >>= 1) v += __shfl_down(v, o, 64);
    return v;
}
__device__ inline float waveReduceMax(float v) {
    for (int o = 32; o; o >>= 1) v = fmaxf(v, __shfl_down(v, o, 64));
    return v;
}

// fp32 -> bf16 bits, RNE
__device__ inline unsigned short f2bf(float x) {
    unsigned u = __float_as_uint(x);
    u += 0x7fffu + ((u >> 16) & 1u);
    return (unsigned short)(u >> 16);
}
__device__ inline float bf2f(unsigned short h) {
    return __uint_as_float((unsigned)h << 16);
}

// -------------------- embedding --------------------
__global__ __launch_bounds__(256) void embed_k(const int* __restrict__ xi,
                                               const float* __restrict__ tok,
                                               const float* __restrict__ pos,
                                               float* __restrict__ h) {
    int idx = blockIdx.x * 256 + threadIdx.x;   // BT*C total
    int row = idx >> 9;        // /512
    int c = idx & 511;
    int t = row & (Tt - 1);
    int token = xi[row];
    h[idx] = tok[(size_t)token * Cc + c] + pos[(size_t)t * Cc + c];
}

// -------------------- layernorm (row of 512), fp32 or bf16-hi/lo output ----
__global__ __launch_bounds__(256) void ln_k(const float* __restrict__ x,
                                            const float* __restrict__ g,
                                            const float* __restrict__ b,
                                            float* __restrict__ of,
                                            unsigned short* __restrict__ ohi,
                                            unsigned short* __restrict__ olo) {
    __shared__ float redA[8];
    int row = blockIdx.x;
    int tid = threadIdx.x, lane = tid & 63, w = tid >> 6;
    const float* xr = x + (size_t)row * Cc;
    float v0 = xr[tid], v1 = xr[tid + 256];
    float s = v0 + v1, sq = v0 * v0 + v1 * v1;
    s = waveReduceSum(s);
    sq = waveReduceSum(sq);
    if (lane == 0) { redA[w] = s; redA[4 + w] = sq; }
    __syncthreads();
    if (tid == 0) {
        redA[0] = redA[0] + redA[1] + redA[2] + redA[3];
        redA[4] = redA[4] + redA[5] + redA[6] + redA[7];
    }
    __syncthreads();
    float mean = redA[0] * (1.0f / Cc);
    float var = redA[4] * (1.0f / Cc) - mean * mean;
    float rstd = rsqrtf(var + 1e-5f);
    float y0 = (v0 - mean) * rstd * g[tid] + b[tid];
    float y1 = (v1 - mean) * rstd * g[tid + 256] + b[tid + 256];
    size_t o0 = (size_t)row * Cc + tid;
    if (ohi) {
        unsigned short h0 = f2bf(y0), h1 = f2bf(y1);
        ohi[o0] = h0;       olo[o0] = f2bf(y0 - bf2f(h0));
        ohi[o0 + 256] = h1; olo[o0 + 256] = f2bf(y1 - bf2f(h1));
    } else {
        of[o0] = y0;
        of[o0 + 256] = y1;
    }
}

// -------------------- OLD generic tiled fp32 GEMM (fallback path) ----------
__global__ __launch_bounds__(256) void gemm_k(const float* __restrict__ A,
                                              const float* __restrict__ W,
                                              const float* __restrict__ bias,
                                              float* __restrict__ Cmat,
                                              int M, int N, int K,
                                              int w_ldk, int w_ldh, int hd_shift,
                                              int flags) {
    __shared__ __align__(16) float As[16][64];
    __shared__ __align__(16) float Bs[16][64];
    int tid = threadIdx.x;
    int tr = tid >> 4, tc = tid & 15;
    int row0 = blockIdx.y * 64;
    int col0 = blockIdx.x * 64;

    int aE = tid * 4;
    int am = aE >> 4;
    int ak = aE & 15;
    int bE = tid * 4;
    int bk = bE >> 6;
    int bn = bE & 63;
    unsigned mask = (1u << hd_shift) - 1u;

    float acc[4][4] = {{0.f}};

    for (int kk = 0; kk < K; kk += 16) {
        float4 av = *(const float4*)(A + (size_t)(row0 + am) * K + kk + ak);
        As[ak + 0][am] = av.x;
        As[ak + 1][am] = av.y;
        As[ak + 2][am] = av.z;
        As[ak + 3][am] = av.w;
#pragma unroll
        for (int i = 0; i < 4; i++) {
            int col = col0 + bn + i;
            float bvv = 0.f;
            if (col < N)
                bvv = W[(size_t)(kk + bk) * w_ldk +
                        (size_t)(col >> hd_shift) * w_ldh + (col & mask)];
            Bs[bk][bn + i] = bvv;
        }
        __syncthreads();
#pragma unroll
        for (int k2 = 0; k2 < 16; k2++) {
            float4 a4 = *(const float4*)&As[k2][tr * 4];
            float4 b4 = *(const float4*)&Bs[k2][tc * 4];
            acc[0][0] += a4.x * b4.x; acc[0][1] += a4.x * b4.y;
            acc[0][2] += a4.x * b4.z; acc[0][3] += a4.x * b4.w;
            acc[1][0] += a4.y * b4.x; acc[1][1] += a4.y * b4.y;
            acc[1][2] += a4.y * b4.z; acc[1][3] += a4.y * b4.w;
            acc[2][0] += a4.z * b4.x; acc[2][1] += a4.z * b4.y;
            acc[2][2] += a4.z * b4.z; acc[2][3] += a4.z * b4.w;
            acc[3][0] += a4.w * b4.x; acc[3][1] += a4.w * b4.y;
            acc[3][2] += a4.w * b4.z; acc[3][3] += a4.w * b4.w;
        }
        __syncthreads();
    }

#pragma unroll
    for (int i = 0; i < 4; i++) {
#pragma unroll
        for (int j = 0; j < 4; j++) {
            int col = col0 + tc * 4 + j;
            if (col < N) {
                size_t idx = (size_t)(row0 + tr * 4 + i) * N + col;
                float vv = acc[i][j];
                if (bias) vv += bias[col];
                if (flags & GF_RELU) vv = fmaxf(vv, 0.f);
                if (flags & GF_RESID) vv += Cmat[idx];
                Cmat[idx] = vv;
            }
        }
    }
}

// -------------------- weight transpose+convert: W[k][n] -> bf16 hi/lo [N][K]
__global__ __launch_bounds__(256) void wt_k(const float* __restrict__ W,
                                            unsigned short* __restrict__ Thi,
                                            unsigned short* __restrict__ Tlo,
                                            int N, int K,
                                            int w_ldk, int w_ldh, int hd_shift) {
    __shared__ float t[32][33];
    int kt = blockIdx.x * 32, nt = blockIdx.y * 32;
    int tid = threadIdx.x;
    int r = tid >> 5, c = tid & 31;
    unsigned mask = (1u << hd_shift) - 1u;
#pragma unroll
    for (int i = 0; i < 4; i++) {
        int k = kt + r + i * 8, n = nt + c;
        float x = 0.f;
        if (n < N)
            x = W[(size_t)k * w_ldk + (size_t)(n >> hd_shift) * w_ldh + (n & mask)];
        t[r + i * 8][c] = x;
    }
    __syncthreads();
#pragma unroll
    for (int i = 0; i < 4; i++) {
        int n = nt + r + i * 8, k = kt + c;
        if (n < N) {
            float x = t[c][r + i * 8];
            unsigned short hi = f2bf(x);
            Thi[(size_t)n * K + k] = hi;
            Tlo[(size_t)n * K + k] = f2bf(x - bf2f(hi));
        }
    }
}

// -------------------- split-bf16 MFMA GEMM core helpers --------------------
__device__ inline void wb_frag(f32x16 v, int rbase, int cbase, int N,
                               const float* __restrict__ bias,
                               float* __restrict__ Cf,
                               unsigned short* __restrict__ Chi,
                               unsigned short* __restrict__ Clo,
                               int flags, int l31, int l5) {
    int col = cbase + l31;
    if (col >= N) return;
    float bv = bias ? bias[col] : 0.0f;
#pragma unroll
    for (int r = 0; r < 16; r++) {
        int row = rbase + (r & 3) + ((r >> 2) << 3) + (l5 << 2);
        size_t idx = (size_t)row * N + col;
        float xv = v[r] + bv;
        if (flags & GF_RELU) xv = fmaxf(xv, 0.0f);
        if (flags & GF_RESID) xv += Cf[idx];
        if (flags & GF_OUTBF16) {
            unsigned short hv = f2bf(xv);
            Chi[idx] = hv;
            Clo[idx] = f2bf(xv - bf2f(hv));
        } else {
            Cf[idx] = xv;
        }
    }
}

#define MFMA3(ACC, AH, AL, BH, BL)                                             \
    ACC = __builtin_amdgcn_mfma_f32_32x32x16_bf16(AH, BH, ACC, 0, 0, 0);       \
    ACC = __builtin_amdgcn_mfma_f32_32x32x16_bf16(AH, BL, ACC, 0, 0, 0);       \
    ACC = __builtin_amdgcn_mfma_f32_32x32x16_bf16(AL, BH, ACC, 0, 0, 0);

// C[M,N] = (Ahi+Alo)[M,K] @ (Whi+Wlo)^T ; W pre-transposed bf16 [N][K].
// 128x128 tile, BK=32, 4 waves of 64x64 (2x2 x 32x32 frags), 3-product split.
__global__ __launch_bounds__(256) void gemm_mfma(
    const unsigned short* __restrict__ Ahg, const unsigned short* __restrict__ Alg,
    const unsigned short* __restrict__ Whg, const unsigned short* __restrict__ Wlg,
    const float* __restrict__ bias, float* __restrict__ Cf,
    unsigned short* __restrict__ Chi, unsigned short* __restrict__ Clo,
    int N, int K, int flags) {
    __shared__ __align__(16) unsigned short Ah[128][40];
    __shared__ __align__(16) unsigned short Al[128][40];
    __shared__ __align__(16) unsigned short Bh[128][40];
    __shared__ __align__(16) unsigned short Bl[128][40];
    int tid = threadIdx.x;
    int row0 = blockIdx.x * 128, col0 = blockIdx.y * 128;
    int sr = tid >> 1, sc = (tid & 1) << 4;       // staging: 2 thr/row, 16 bf16 each
    int lane = tid & 63, w = tid >> 6;
    int wrow = (w >> 1) << 6, wcol = (w & 1) << 6;
    int l31 = lane & 31, l5 = lane >> 5;

    const unsigned short* ap  = Ahg + (size_t)(row0 + sr) * K + sc;
    const unsigned short* alp = Alg + (size_t)(row0 + sr) * K + sc;
    int bn = col0 + sr;
    bool bok = bn < N;
    const unsigned short* bp  = Whg + (size_t)bn * K + sc;
    const unsigned short* blp = Wlg + (size_t)bn * K + sc;

    f32x16 acc00, acc01, acc10, acc11;
#pragma unroll
    for (int r = 0; r < 16; r++) {
        acc00[r] = 0.f; acc01[r] = 0.f; acc10[r] = 0.f; acc11[r] = 0.f;
    }

    uint4 zz; zz.x = zz.y = zz.z = zz.w = 0u;
    uint4 ra0 = *(const uint4*)(ap);
    uint4 ra1 = *(const uint4*)(ap + 8);
    uint4 ra2 = *(const uint4*)(alp);
    uint4 ra3 = *(const uint4*)(alp + 8);
    uint4 rb0 = zz, rb1 = zz, rb2 = zz, rb3 = zz;
    if (bok) {
        rb0 = *(const uint4*)(bp);
        rb1 = *(const uint4*)(bp + 8);
        rb2 = *(const uint4*)(blp);
        rb3 = *(const uint4*)(blp + 8);
    }

    for (int kk = 0; kk < K; kk += 32) {
        *(uint4*)&Ah[sr][sc] = ra0; *(uint4*)&Ah[sr][sc + 8] = ra1;
        *(uint4*)&Al[sr][sc] = ra2; *(uint4*)&Al[sr][sc + 8] = ra3;
        *(uint4*)&Bh[sr][sc] = rb0; *(uint4*)&Bh[sr][sc + 8] = rb1;
        *(uint4*)&Bl[sr][sc] = rb2; *(uint4*)&Bl[sr][sc + 8] = rb3;
        if (kk + 32 < K) {   // prefetch next tile into regs (hides HBM latency)
            int k2 = kk + 32;
            ra0 = *(const uint4*)(ap + k2);
            ra1 = *(const uint4*)(ap + k2 + 8);
            ra2 = *(const uint4*)(alp + k2);
            ra3 = *(const uint4*)(alp + k2 + 8);
            if (bok) {
                rb0 = *(const uint4*)(bp + k2);
                rb1 = *(const uint4*)(bp + k2 + 8);
                rb2 = *(const uint4*)(blp + k2);
                rb3 = *(const uint4*)(blp + k2 + 8);
            }
        }
        __syncthreads();
#pragma unroll
        for (int ks = 0; ks < 2; ks++) {
            int ko = (ks << 4) + (l5 << 3);
            bf16x8 a0h = *(const bf16x8*)&Ah[wrow + l31][ko];
            bf16x8 a1h = *(const bf16x8*)&Ah[wrow + 32 + l31][ko];
            bf16x8 a0l = *(const bf16x8*)&Al[wrow + l31][ko];
            bf16x8 a1l = *(const bf16x8*)&Al[wrow + 32 + l31][ko];
            bf16x8 b0h = *(const bf16x8*)&Bh[wcol + l31][ko];
            bf16x8 b1h = *(const bf16x8*)&Bh[wcol + 32 + l31][ko];
            bf16x8 b0l = *(const bf16x8*)&Bl[wcol + l31][ko];
            bf16x8 b1l = *(const bf16x8*)&Bl[wcol + 32 + l31][ko];
            MFMA3(acc00, a0h, a0l, b0h, b0l)
            MFMA3(acc01, a0h, a0l, b1h, b1l)
            MFMA3(acc10, a1h, a1l, b0h, b0l)
            MFMA3(acc11, a1h, a1l, b1h, b1l)
        }
        __syncthreads();
    }

    wb_frag(acc00, row0 + wrow,      col0 + wcol,      N, bias, Cf, Chi, Clo, flags, l31, l5);
    wb_frag(acc01, row0 + wrow,      col0 + wcol + 32, N, bias, Cf, Chi, Clo, flags, l31, l5);
    wb_frag(acc10, row0 + wrow + 32, col0 + wcol,      N, bias, Cf, Chi, Clo, flags, l31, l5);
    wb_frag(acc11, row0 + wrow + 32, col0 + wcol + 32, N, bias, Cf, Chi, Clo, flags, l31, l5);
}

// LM-head variant: B staged on the fly from fp32 W [K][N] (saves 103MB ws).
__global__ __launch_bounds__(256) void gemm_mfma_wf32(
    const unsigned short* __restrict__ Ahg, const unsigned short* __restrict__ Alg,
    const float* __restrict__ W, const float* __restrict__ bias,
    float* __restrict__ Cf, int N, int K) {
    __shared__ __align__(16) unsigned short Ah[128][40];
    __shared__ __align__(16) unsigned short Al[128][40];
    __shared__ __align__(16) unsigned short Bh[128][40];
    __shared__ __align__(16) unsigned short Bl[128][40];
    int tid = threadIdx.x;
    int row0 = blockIdx.x * 128, col0 = blockIdx.y * 128;
    int sr = tid >> 1, sc = (tid & 1) << 4;
    int lane = tid & 63, w = tid >> 6;
    int wrow = (w >> 1) << 6, wcol = (w & 1) << 6;
    int l31 = lane & 31, l5 = lane >> 5;
    int krow = tid >> 3, nb = tid & 7;            // B staging: 8 thr/k-row

    const unsigned short* ap  = Ahg + (size_t)(row0 + sr) * K + sc;
    const unsigned short* alp = Alg + (size_t)(row0 + sr) * K + sc;

    f32x16 acc00, acc01, acc10, acc11;
#pragma unroll
    for (int r = 0; r < 16; r++) {
        acc00[r] = 0.f; acc01[r] = 0.f; acc10[r] = 0.f; acc11[r] = 0.f;
    }

    for (int kk = 0; kk < K; kk += 32) {
        uint4 ra0 = *(const uint4*)(ap + kk);
        uint4 ra1 = *(const uint4*)(ap + kk + 8);
        uint4 ra2 = *(const uint4*)(alp + kk);
        uint4 ra3 = *(const uint4*)(alp + kk + 8);
        *(uint4*)&Ah[sr][sc] = ra0; *(uint4*)&Ah[sr][sc + 8] = ra1;
        *(uint4*)&Al[sr][sc] = ra2; *(uint4*)&Al[sr][sc + 8] = ra3;
        const float* wp = W + (size_t)(kk + krow) * N + col0 + nb;
#pragma unroll
        for (int j = 0; j < 16; j++) {
            int c = col0 + nb + (j << 3);
            float x = (c < N) ? wp[j << 3] : 0.0f;
            unsigned short hv = f2bf(x);
            Bh[nb + (j << 3)][krow] = hv;
            Bl[nb + (j << 3)][krow] = f2bf(x - bf2f(hv));
        }
        __syncthreads();
#pragma unroll
        for (int ks = 0; ks < 2; ks++) {
            int ko = (ks << 4) + (l5 << 3);
            bf16x8 a0h = *(const bf16x8*)&Ah[wrow + l31][ko];
            bf16x8 a1h = *(const bf16x8*)&Ah[wrow + 32 + l31][ko];
            bf16x8 a0l = *(const bf16x8*)&Al[wrow + l31][ko];
            bf16x8 a1l = *(const bf16x8*)&Al[wrow + 32 + l31][ko];
            bf16x8 b0h = *(const bf16x8*)&Bh[wcol + l31][ko];
            bf16x8 b1h = *(const bf16x8*)&Bh[wcol + 32 + l31][ko];
            bf16x8 b0l = *(const bf16x8*)&Bl[wcol + l31][ko];
            bf16x8 b1l = *(const bf16x8*)&Bl[wcol + 32 + l31][ko];
            MFMA3(acc00, a0h, a0l, b0h, b0l)
            MFMA3(acc01, a0h, a0l, b1h, b1l)
            MFMA3(acc10, a1h, a1l, b0h, b0l)
            MFMA3(acc11, a1h, a1l, b1h, b1l)
        }
        __syncthreads();
    }

    wb_frag(acc00, row0 + wrow,      col0 + wcol,      N, bias, Cf, nullptr, nullptr, 0, l31, l5);
    wb_frag(acc01, row0 + wrow,      col0 + wcol + 32, N, bias, Cf, nullptr, nullptr, 0, l31, l5);
    wb_frag(acc10, row0 + wrow + 32, col0 + wcol,      N, bias, Cf, nullptr, nullptr, 0, l31, l5);
    wb_frag(acc11, row0 + wrow + 32, col0 + wcol + 32, N, bias, Cf, nullptr, nullptr, 0, l31, l5);
}

// -------------------- flash attention (MFMA, causal) -----------------------
// Grid: 256 blocks = (b,h,q-tile of 128). 4 waves x 32 q-rows each.
// KV tiles of 64 staged in LDS: Ksm[kv][d], Vsm[d][kv] (transposed), both
// XOR-swizzled (ushort idx ^= (row&7)<<3) to break stride-128B bank conflicts.
// Online softmax per q-row; row-sum l computed via MFMA with all-ones B-frag.
__global__ __launch_bounds__(256) void attn_flash(const float* __restrict__ q,
                                                  const float* __restrict__ k,
                                                  const float* __restrict__ v,
                                                  unsigned short* __restrict__ ohi,
                                                  unsigned short* __restrict__ olo) {
    __shared__ __align__(16) unsigned short Ksm[64 * 64];
    __shared__ __align__(16) unsigned short Vsm[64 * 64];
    __shared__ __align__(16) unsigned short Psm[4 * 32 * 64];
    int tid = threadIdx.x;
    int lane = tid & 63, w = tid >> 6;
    int l31 = lane & 31, l5 = lane >> 5;
    int blk = blockIdx.x;
    int qt = blk & 15, bh = blk >> 4;
    int b = bh >> 3, h = bh & 7;
    int q0 = qt * 128;
    int qw0 = q0 + w * 32;
    size_t rowbase = (size_t)b * Tt * Cc + (size_t)h * HDim;

    // Q fragments (scale 0.125 folded in), row = qw0 + l31
    bf16x8 qf[4];
    {
        const float* qrow = q + rowbase + (size_t)(qw0 + l31) * Cc;
#pragma unroll
        for (int ks = 0; ks < 4; ks++) {
            unsigned short tq[8];
            int d0 = ks * 16 + l5 * 8;
#pragma unroll
            for (int j = 0; j < 8; j++) tq[j] = f2bf(qrow[d0 + j] * 0.125f);
            qf[ks] = *(bf16x8*)tq;
        }
    }

    f32x16 o0, o1, lacc;
    float mrow[16];
#pragma unroll
    for (int r = 0; r < 16; r++) { o0[r] = 0.f; o1[r] = 0.f; lacc[r] = 0.f; mrow[r] = -3.0e38f; }

    unsigned short ob[8];
#pragma unroll
    for (int j = 0; j < 8; j++) ob[j] = 0x3F80;  // bf16 1.0
    bf16x8 ones = *(bf16x8*)ob;

    int nt = q0 / 64 + 2;                 // kv tiles of 64
    int skv = tid >> 2, sd4 = (tid & 3) * 16;   // staging: 4 thr/kv-row, 16 d each
    int ssw = (skv & 7) << 3;
    int lsw = (l31 & 7) << 3;

    float4 kr[4], vr[4];
    {
        const float* kp = k + rowbase + (size_t)skv * Cc + sd4;
        const float* vp = v + rowbase + (size_t)skv * Cc + sd4;
#pragma unroll
        for (int i = 0; i < 4; i++) { kr[i] = *(const float4*)(kp + 4 * i); vr[i] = *(const float4*)(vp + 4 * i); }
    }

    for (int t = 0; t < nt; t++) {
        int kv0 = t * 64;
        __syncthreads();   // previous tile's LDS reads done
        // ---- write staged regs to LDS ----
        {
            unsigned short tk[16], tv[16];
#pragma unroll
            for (int i = 0; i < 4; i++) {
                tk[4 * i + 0] = f2bf(kr[i].x); tk[4 * i + 1] = f2bf(kr[i].y);
                tk[4 * i + 2] = f2bf(kr[i].z); tk[4 * i + 3] = f2bf(kr[i].w);
                tv[4 * i + 0] = f2bf(vr[i].x); tv[4 * i + 1] = f2bf(vr[i].y);
                tv[4 * i + 2] = f2bf(vr[i].z); tv[4 * i + 3] = f2bf(vr[i].w);
            }
            int rb = skv * 64;
            *(uint4*)&Ksm[rb + (sd4 ^ ssw)]       = *(uint4*)&tk[0];
            *(uint4*)&Ksm[rb + ((sd4 + 8) ^ ssw)] = *(uint4*)&tk[8];
#pragma unroll
            for (int i = 0; i < 16; i++) {
                int d = sd4 + i;
                Vsm[d * 64 + (skv ^ ((d & 7) << 3))] = tv[i];
            }
        }
        __syncthreads();
        // ---- prefetch next tile ----
        if (t + 1 < nt) {
            const float* kp = k + rowbase + (size_t)((t + 1) * 64 + skv) * Cc + sd4;
            const float* vp = v + rowbase + (size_t)((t + 1) * 64 + skv) * Cc + sd4;
#pragma unroll
            for (int i = 0; i < 4; i++) { kr[i] = *(const float4*)(kp + 4 * i); vr[i] = *(const float4*)(vp + 4 * i); }
        }
        // ---- compute (skip tiles fully above this wave's diagonal) ----
        if (kv0 <= qw0 + 31) {
            f32x16 s0, s1;
#pragma unroll
            for (int r = 0; r < 16; r++) { s0[r] = 0.f; s1[r] = 0.f; }
#pragma unroll
            for (int ks = 0; ks < 4; ks++) {
                int kc = ks * 16 + l5 * 8;
                bf16x8 k0 = *(const bf16x8*)&Ksm[l31 * 64 + (kc ^ lsw)];
                bf16x8 k1 = *(const bf16x8*)&Ksm[(l31 + 32) * 64 + (kc ^ lsw)];
                s0 = __builtin_amdgcn_mfma_f32_32x32x16_bf16(qf[ks], k0, s0, 0, 0, 0);
                s1 = __builtin_amdgcn_mfma_f32_32x32x16_bf16(qf[ks], k1, s1, 0, 0, 0);
            }
            bool needmask = (kv0 + 63 > qw0);
            int relq = qw0 - kv0;
            float nm[16];
#pragma unroll
            for (int r = 0; r < 16; r++) {
                int R = (r & 3) + ((r >> 2) << 3) + (l5 << 2);
                float a = s0[r], c = s1[r];
                if (needmask) {
                    if (l31 > relq + R) a = -3.0e38f;
                    if (l31 + 32 > relq + R) c = -3.0e38f;
                }
                s0[r] = a; s1[r] = c;
                float mx = fmaxf(a, c);
#pragma unroll
                for (int off = 1; off < 32; off <<= 1) mx = fmaxf(mx, __shfl_xor(mx, off, 64));
                nm[r] = fmaxf(mrow[r], mx);
            }
            unsigned short* Pw = &Psm[w * 2048];
#pragma unroll
            for (int r = 0; r < 16; r++) {
                float sc = __expf(mrow[r] - nm[r]);
                mrow[r] = nm[r];
                o0[r] *= sc; o1[r] *= sc; lacc[r] *= sc;
                float p0 = __expf(s0[r] - nm[r]);
                float p1 = __expf(s1[r] - nm[r]);
                int R = (r & 3) + ((r >> 2) << 3) + (l5 << 2);
                int sw = (R & 7) << 3;
                Pw[R * 64 + (l31 ^ sw)] = f2bf(p0);
                Pw[R * 64 + ((l31 + 32) ^ sw)] = f2bf(p1);
            }
#pragma unroll
            for (int ch = 0; ch < 4; ch++) {
                int kc = ch * 16 + l5 * 8;
                bf16x8 pf = *(const bf16x8*)&Pw[l31 * 64 + (kc ^ lsw)];
                bf16x8 v0 = *(const bf16x8*)&Vsm[l31 * 64 + (kc ^ lsw)];
                bf16x8 v1 = *(const bf16x8*)&Vsm[(l31 + 32) * 64 + (kc ^ lsw)];
                o0   = __builtin_amdgcn_mfma_f32_32x32x16_bf16(pf, v0, o0, 0, 0, 0);
                o1   = __builtin_amdgcn_mfma_f32_32x32x16_bf16(pf, v1, o1, 0, 0, 0);
                lacc = __builtin_amdgcn_mfma_f32_32x32x16_bf16(pf, ones, lacc, 0, 0, 0);
            }
        }
    }

    // ---- epilogue: O/l -> bf16 hi/lo ----
#pragma unroll
    for (int r = 0; r < 16; r++) {
        int R = (r & 3) + ((r >> 2) << 3) + (l5 << 2);
        float inv = 1.0f / lacc[r];
        size_t o = rowbase + (size_t)(qw0 + R) * Cc;
        float x0 = o0[r] * inv, x1 = o1[r] * inv;
        unsigned short h0 = f2bf(x0), h1 = f2bf(x1);
        ohi[o + l31] = h0;        olo[o + l31] = f2bf(x0 - bf2f(h0));
        ohi[o + 32 + l31] = h1;   olo[o + 32 + l31] = f2bf(x1 - bf2f(h1));
    }
}

// -------------------- old causal attention (fallback path) -----------------
__global__ __launch_bounds__(256) void attn_k(const float* __restrict__ q,
                                              const float* __restrict__ k,
                                              const float* __restrict__ v,
                                              float* __restrict__ outf,
                                              unsigned short* __restrict__ ohi,
                                              unsigned short* __restrict__ olo) {
    __shared__ float sc[Tt];
    __shared__ float qs[HDim];
    __shared__ float pacc[256];
    __shared__ float redA[4];
    __shared__ float fin[2];
    int tq = blockIdx.x;
    int bh = blockIdx.y;
    int b = bh >> 3, h = bh & 7;
    int tid = threadIdx.x, lane = tid & 63, w = tid >> 6;
    size_t base = (size_t)b * Tt * Cc + (size_t)h * HDim;
    if (tid < HDim) qs[tid] = q[base + (size_t)tq * Cc + tid] * 0.125f;
    __syncthreads();
    for (int s = w; s <= tq; s += 4) {
        float val = qs[lane] * k[base + (size_t)s * Cc + lane];
        val = waveReduceSum(val);
        if (lane == 0) sc[s] = val;
    }
    __syncthreads();
    float m = -3.0e38f;
    for (int i = tid; i <= tq; i += 256) m = fmaxf(m, sc[i]);
    m = waveReduceMax(m);
    if (lane == 0) redA[w] = m;
    __syncthreads();
    if (tid == 0) fin[0] = fmaxf(fmaxf(redA[0], redA[1]), fmaxf(redA[2], redA[3]));
    __syncthreads();
    m = fin[0];
    float sum = 0.f;
    for (int i = tid; i <= tq; i += 256) {
        float e = __expf(sc[i] - m);
        sc[i] = e;
        sum += e;
    }
    sum = waveReduceSum(sum);
    if (lane == 0) redA[w] = sum;
    __syncthreads();
    if (tid == 0) fin[1] = redA[0] + redA[1] + redA[2] + redA[3];
    __syncthreads();
    float inv = 1.0f / fin[1];
    float acc = 0.f;
    for (int s = w; s <= tq; s += 4)
        acc += sc[s] * v[base + (size_t)s * Cc + lane];
    pacc[tid] = acc;
    __syncthreads();
    if (w == 0) {
        float r = (pacc[lane] + pacc[64 + lane] + pacc[128 + lane] + pacc[192 + lane]) * inv;
        size_t oi = base + (size_t)tq * Cc + lane;
        if (ohi) {
            unsigned short hv = f2bf(r);
            ohi[oi] = hv;
            olo[oi] = f2bf(r - bf2f(hv));
        } else {
            outf[oi] = r;
        }
    }
}

// -------------------- per-row loss term --------------------
__global__ __launch_bounds__(256) void lse_k(const float* __restrict__ logits,
                                             const int* __restrict__ tgt,
                                             float* __restrict__ rowloss) {
    __shared__ float redA[4];
    __shared__ float fin[2];
    int r = blockIdx.x;
    int tid = threadIdx.x, lane = tid & 63, w = tid >> 6;
    const float* p = logits + (size_t)r * Vv;
    float m = -3.0e38f;
    for (int i = tid; i < Vv; i += 256) m = fmaxf(m, p[i]);
    m = waveReduceMax(m);
    if (lane == 0) redA[w] = m;
    __syncthreads();
    if (tid == 0) fin[0] = fmaxf(fmaxf(redA[0], redA[1]), fmaxf(redA[2], redA[3]));
    __syncthreads();
    float bm = fin[0];
    float sum = 0.f;
    for (int i = tid; i < Vv; i += 256) sum += __expf(p[i] - bm);
    sum = waveReduceSum(sum);
    if (lane == 0) redA[w] = sum;
    __syncthreads();
    if (tid == 0) fin[1] = redA[0] + redA[1] + redA[2] + redA[3];
    __syncthreads();
    if (tid == 0) rowloss[r] = p[tgt[r]] - bm - logf(fin[1]);
}

__global__ __launch_bounds__(256) void loss_k(const float* __restrict__ rowloss,
                                              float* __restrict__ out) {
    __shared__ float redA[4];
    int tid = threadIdx.x, lane = tid & 63, w = tid >> 6;
    float s = 0.f;
    for (int i = tid; i < BT; i += 256) s += rowloss[i];
    s = waveReduceSum(s);
    if (lane == 0) redA[w] = s;
    __syncthreads();
    if (tid == 0) out[0] = -(redA[0] + redA[1] + redA[2] + redA[3]) * (1.0f / BT);
}

extern "C" void kernel_launch(void* const* d_in, const int* in_sizes, int n_in,
                              void* d_out, int out_size, void* d_ws, size_t ws_size,
                              hipStream_t stream) {
    const int*   x     = (const int*)d_in[0];
    const int*   tgt   = (const int*)d_in[1];
    const float* tok   = (const float*)d_in[2];
    const float* pos   = (const float*)d_in[3];
    const float* ln1s  = (const float*)d_in[4];
    const float* ln1b  = (const float*)d_in[5];
    const float* wq    = (const float*)d_in[6];
    const float* wk    = (const float*)d_in[7];
    const float* wv    = (const float*)d_in[8];
    const float* wproj = (const float*)d_in[9];
    const float* bproj = (const float*)d_in[10];
    const float* ln2s  = (const float*)d_in[11];
    const float* ln2b  = (const float*)d_in[12];
    const float* wff1  = (const float*)d_in[13];
    const float* bff1  = (const float*)d_in[14];
    const float* wff2  = (const float*)d_in[15];
    const float* bff2  = (const float*)d_in[16];
    const float* lnfs  = (const float*)d_in[17];
    const float* lnfb  = (const float*)d_in[18];
    const float* lmw   = (const float*)d_in[19];
    const float* lmb   = (const float*)d_in[20];

    float* logits = (float*)d_out;
    float* lossp = logits + (size_t)BT * Vv;

    const size_t rowsC = (size_t)BT * Cc;       // 2,097,152
    const size_t midE  = (size_t)BT * FF;       // 8,388,608
    const size_t lwEl  = (size_t)Cc * Cc;       // 262,144 (qkv/proj weight elems)
    const size_t ffEl  = (size_t)Cc * FF;       // 1,048,576
    const size_t layerUS = 8 * lwEl + 4 * ffEl; // ushorts per layer of hi/lo weights

    // ---- new-path workspace layout ----
    char* p = (char*)d_ws;
    float* h  = (float*)p; p += rowsC * 4;
    float* qb = (float*)p; p += rowsC * 4;
    float* kb = (float*)p; p += rowsC * 4;
    float* vb = (float*)p; p += rowsC * 4;
    float* rowloss = (float*)p; p += (size_t)BT * 4;
    unsigned short* ahi = (unsigned short*)p; p += rowsC * 2;
    unsigned short* alo = (unsigned short*)p; p += rowsC * 2;
    unsigned short* midhi = (unsigned short*)p; p += midE * 2;
    unsigned short* midlo = (unsigned short*)p; p += midE * 2;
    unsigned short* wt = (unsigned short*)p; p += 4 * layerUS * 2;
    size_t needNew = (size_t)(p - (char*)d_ws);

    if (ws_size >= needNew) {
        // ================== MFMA split-bf16 path ==================
        for (int l = 0; l < Lnum; l++) {
            unsigned short* Lw = wt + (size_t)l * layerUS;
            const float* wq_l = wq + (size_t)l * Hn * Cc * HDim;
            const float* wk_l = wk + (size_t)l * Hn * Cc * HDim;
            const float* wv_l = wv + (size_t)l * Hn * Cc * HDim;
            wt_k<<<dim3(16, 16), 256, 0, stream>>>(wq_l, Lw, Lw + lwEl,
                                                   Cc, Cc, HDim, Cc * HDim, 6);
            wt_k<<<dim3(16, 16), 256, 0, stream>>>(wk_l, Lw + 2 * lwEl, Lw + 3 * lwEl,
                                                   Cc, Cc, HDim, Cc * HDim, 6);
            wt_k<<<dim3(16, 16), 256, 0, stream>>>(wv_l, Lw + 4 * lwEl, Lw + 5 * lwEl,
                                                   Cc, Cc, HDim, Cc * HDim, 6);
            wt_k<<<dim3(16, 16), 256, 0, stream>>>(wproj + (size_t)l * Cc * Cc,
                                                   Lw + 6 * lwEl, Lw + 7 * lwEl,
                                                   Cc, Cc, Cc, 0, 30);
            wt_k<<<dim3(16, 64), 256, 0, stream>>>(wff1 + (size_t)l * Cc * FF,
                                                   Lw + 8 * lwEl, Lw + 8 * lwEl + ffEl,
                                                   FF, Cc, FF, 0, 30);
            wt_k<<<dim3(64, 16), 256, 0, stream>>>(wff2 + (size_t)l * FF * Cc,
                                                   Lw + 8 * lwEl + 2 * ffEl,
                                                   Lw + 8 * lwEl + 3 * ffEl,
                                                   Cc, FF, Cc, 0, 30);
        }

        embed_k<<<(BT * Cc) / 256, 256, 0, stream>>>(x, tok, pos, h);

        dim3 g512(BT / 128, Cc / 128);   // (32, 4)
        dim3 gff1(BT / 128, FF / 128);   // (32, 16)

        for (int l = 0; l < Lnum; l++) {
            unsigned short* Lw = wt + (size_t)l * layerUS;
            ln_k<<<BT, 256, 0, stream>>>(h, ln1s + l * Cc, ln1b + l * Cc,
                                         nullptr, ahi, alo);
            gemm_mfma<<<g512, 256, 0, stream>>>(ahi, alo, Lw, Lw + lwEl,
                                                nullptr, qb, nullptr, nullptr,
                                                Cc, Cc, 0);
            gemm_mfma<<<g512, 256, 0, stream>>>(ahi, alo, Lw + 2 * lwEl, Lw + 3 * lwEl,
                                                nullptr, kb, nullptr, nullptr,
                                                Cc, Cc, 0);
            gemm_mfma<<<g512, 256, 0, stream>>>(ahi, alo, Lw + 4 * lwEl, Lw + 5 * lwEl,
                                                nullptr, vb, nullptr, nullptr,
                                                Cc, Cc, 0);
            attn_flash<<<256, 256, 0, stream>>>(qb, kb, vb, ahi, alo);
            gemm_mfma<<<g512, 256, 0, stream>>>(ahi, alo, Lw + 6 * lwEl, Lw + 7 * lwEl,
                                                bproj + l * Cc, h, nullptr, nullptr,
                                                Cc, Cc, GF_RESID);
            ln_k<<<BT, 256, 0, stream>>>(h, ln2s + l * Cc, ln2b + l * Cc,
                                         nullptr, ahi, alo);
            gemm_mfma<<<gff1, 256, 0, stream>>>(ahi, alo, Lw + 8 * lwEl,
                                                Lw + 8 * lwEl + ffEl,
                                                bff1 + l * FF, nullptr, midhi, midlo,
                                                FF, Cc, GF_RELU | GF_OUTBF16);
            gemm_mfma<<<g512, 256, 0, stream>>>(midhi, midlo, Lw + 8 * lwEl + 2 * ffEl,
                                                Lw + 8 * lwEl + 3 * ffEl,
                                                bff2 + l * Cc, h, nullptr, nullptr,
                                                Cc, FF, GF_RESID);
        }

        ln_k<<<BT, 256, 0, stream>>>(h, lnfs, lnfb, nullptr, ahi, alo);
        dim3 glm(BT / 128, (Vv + 127) / 128);   // (32, 393)
        gemm_mfma_wf32<<<glm, 256, 0, stream>>>(ahi, alo, lmw, lmb, logits, Vv, Cc);
        lse_k<<<BT, 256, 0, stream>>>(logits, tgt, rowloss);
        loss_k<<<1, 256, 0, stream>>>(rowloss, lossp);
    } else {
        // ================== fallback: original fp32 path ==================
        float* ws = (float*)d_ws;
        float* h2   = ws;
        float* a2   = h2 + rowsC;
        float* qb2  = a2 + rowsC;
        float* kb2  = qb2 + rowsC;
        float* vb2  = kb2 + rowsC;
        float* mid2 = vb2 + rowsC;                    // BT*FF
        float* rowloss2 = mid2 + (size_t)BT * FF;
        if (ws_size < (5 * rowsC + (size_t)BT * FF + BT) * sizeof(float)) return;

        embed_k<<<(BT * Cc) / 256, 256, 0, stream>>>(x, tok, pos, h2);

        dim3 g512(Cc / 64, BT / 64);
        dim3 gff1(FF / 64, BT / 64);
        dim3 gattn(Tt, 2 * Hn);

        for (int l = 0; l < Lnum; l++) {
            const float* wq_l = wq + (size_t)l * Hn * Cc * HDim;
            const float* wk_l = wk + (size_t)l * Hn * Cc * HDim;
            const float* wv_l = wv + (size_t)l * Hn * Cc * HDim;
            ln_k<<<BT, 256, 0, stream>>>(h2, ln1s + l * Cc, ln1b + l * Cc,
                                         a2, nullptr, nullptr);
            gemm_k<<<g512, 256, 0, stream>>>(a2, wq_l, nullptr, qb2, BT, Cc, Cc,
                                             HDim, Cc * HDim, 6, 0);
            gemm_k<<<g512, 256, 0, stream>>>(a2, wk_l, nullptr, kb2, BT, Cc, Cc,
                                             HDim, Cc * HDim, 6, 0);
            gemm_k<<<g512, 256, 0, stream>>>(a2, wv_l, nullptr, vb2, BT, Cc, Cc,
                                             HDim, Cc * HDim, 6, 0);
            attn_k<<<gattn, 256, 0, stream>>>(qb2, kb2, vb2, a2, nullptr, nullptr);
            gemm_k<<<g512, 256, 0, stream>>>(a2, wproj + (size_t)l * Cc * Cc,
                                             bproj + l * Cc, h2, BT, Cc, Cc,
                                             Cc, 0, 30, GF_RESID);
            ln_k<<<BT, 256, 0, stream>>>(h2, ln2s + l * Cc, ln2b + l * Cc,
                                         a2, nullptr, nullptr);
            gemm_k<<<gff1, 256, 0, stream>>>(a2, wff1 + (size_t)l * Cc * FF,
                                             bff1 + l * FF, mid2, BT, FF, Cc,
                                             FF, 0, 30, GF_RELU);
            gemm_k<<<g512, 256, 0, stream>>>(mid2, wff2 + (size_t)l * FF * Cc,
                                             bff2 + l * Cc, h2, BT, Cc, FF,
                                             Cc, 0, 30, GF_RESID);
        }

        ln_k<<<BT, 256, 0, stream>>>(h2, lnfs, lnfb, a2, nullptr, nullptr);
        dim3 glog((Vv + 63) / 64, BT / 64);
        gemm_k<<<glog, 256, 0, stream>>>(a2, lmw, lmb, logits, BT, Vv, Cc,
                                         Vv, 0, 30, 0);
        lse_k<<<BT, 256, 0, stream>>>(logits, tgt, rowloss2);
        loss_k<<<1, 256, 0, stream>>>(rowloss2, lossp);
    }
}